// Round 1
// 657.040 us; speedup vs baseline: 1.0831x; 1.0831x over previous
//
#include <hip/hip_runtime.h>
#include <hip/hip_bf16.h>

#define Bn 4
#define C1n 256
#define C2n 128
#define CF 384
#define HWn 65536
#define Kc 128
#define Nn 512          // B*K
#define En 256
#define NCn 16
#define Gn 512
#define Rn 64
#define HEADSn 8
#define DHn 32

#define CHK 32          // chunks per image
#define PCH2 (HWn/CHK)  // 2048 pixels per chunk
#define TC2 32          // channels per block
#define NT 64           // pixels per tile

#define SCALE_F 1048576.0f
#define INV_SCALE (1.0f/1048576.0f)

typedef unsigned long long ull;

// ---------------- area histogram: per-chunk partial counts, no atomics -------
__global__ __launch_bounds__(256) void area_k(const int* __restrict__ mask,
                                              int* __restrict__ apart) {
    int chunk = blockIdx.x, b = blockIdx.y;
    __shared__ int hist[4][129];
    int t = threadIdx.x, w = t >> 6;
    for (int i = t; i < 4 * 129; i += 256) ((int*)hist)[i] = 0;
    __syncthreads();
    const int* mp = mask + (size_t)b * HWn + chunk * PCH2;
    #pragma unroll
    for (int it = 0; it < PCH2 / 1024; ++it) {
        int4 v = *(const int4*)(mp + it * 1024 + t * 4);
        atomicAdd(&hist[w][v.x], 1);
        atomicAdd(&hist[w][v.y], 1);
        atomicAdd(&hist[w][v.z], 1);
        atomicAdd(&hist[w][v.w], 1);
    }
    __syncthreads();
    if (t < 128)
        apart[(chunk * Bn + b) * Kc + t] =
            hist[0][t+1] + hist[1][t+1] + hist[2][t+1] + hist[3][t+1];
}

// ---------------- segment reduce: i32 fixed-point LDS atomics, slab partials -
// grid (32 chunks, 12 ch-groups, 4 batches), 256 threads
// Per-chunk bin sums are bounded: |sum| <= ~2048 (32-sigma of N(0,2048)) so
// i32 at 2^20 scale cannot overflow; i32 totals reduce bit-exactly into i64.
__global__ __launch_bounds__(256) void segreduce3_k(
        const float* __restrict__ hd1, const float* __restrict__ h1,
        const int* __restrict__ mask,
        int* __restrict__ spart) {
    int chunk = blockIdx.x, cg = blockIdx.y, b = blockIdx.z;
    int c0 = cg * TC2;
    const float* base = (c0 < C1n)
        ? hd1 + ((size_t)(b * C1n + c0)) * HWn
        : h1  + ((size_t)(b * C2n + (c0 - C1n))) * HWn;
    const int* mp = mask + (size_t)b * HWn + chunk * PCH2;

    __shared__ int bins[129 * TC2];            // 16.5 KB
    __shared__ float tile[NT * 33];            // 8.4 KB [px][33]
    __shared__ __align__(16) int idsh[NT];

    int t = threadIdx.x;
    int cL = t >> 3, l8 = t & 7;               // load mapping
    int cA = t & 31, pg = t >> 5;              // atomic mapping
    for (int i = t; i < 129 * TC2; i += 256) bins[i] = 0;
    __syncthreads();

    for (int tl = 0; tl < PCH2 / NT; ++tl) {
        int px0 = tl * NT;
        // coalesced global loads: 128-B segments per channel row
        float4 v0 = *(const float4*)(base + (size_t)cL * HWn + px0 + l8 * 4);
        float4 v1 = *(const float4*)(base + (size_t)cL * HWn + px0 + 32 + l8 * 4);
        if (t < 16) *(int4*)&idsh[t * 4] = *(const int4*)(mp + px0 + t * 4);
        // transpose into [px][33]
        int p0 = l8 * 4;
        tile[(p0 + 0) * 33 + cL] = v0.x;
        tile[(p0 + 1) * 33 + cL] = v0.y;
        tile[(p0 + 2) * 33 + cL] = v0.z;
        tile[(p0 + 3) * 33 + cL] = v0.w;
        tile[(32 + p0 + 0) * 33 + cL] = v1.x;
        tile[(32 + p0 + 1) * 33 + cL] = v1.y;
        tile[(32 + p0 + 2) * 33 + cL] = v1.z;
        tile[(32 + p0 + 3) * 33 + cL] = v1.w;
        __syncthreads();
        #pragma unroll
        for (int pp = 0; pp < 8; ++pp) {
            int p = pg * 8 + pp;
            int id = idsh[p];
            float v = tile[p * 33 + cA];
            int qv = __float2int_rn(v * SCALE_F);
            atomicAdd(&bins[id * TC2 + cA], qv);   // native ds_add_u32, 2-way banks
        }
        __syncthreads();
    }
    // flush: plain coalesced stores of the full partial slab (zeros included,
    // so no pre-zeroing of the workspace is needed)
    for (int i = t; i < 129 * TC2; i += 256) {
        int cell = i >> 5, cc = i & 31;
        spart[((size_t)(chunk * Bn + b) * 129 + cell) * CF + c0 + cc] = bins[i];
    }
}

// ---------------- reduce per-chunk i32 partials -> f32 cell totals ----------
// ctot layout: [b][cell 0..128][c]  (cell 0 = background, used only for glob)
__global__ void reduce_k(const int* __restrict__ spart, float* __restrict__ ctot) {
    int idx = blockIdx.x * 256 + threadIdx.x;      // over 4*129*384 = 198144
    if (idx >= Bn * 129 * CF) return;
    int b = idx / (129 * CF);
    int rem = idx - b * 129 * CF;                  // cell*CF + c
    long long s = 0;
    #pragma unroll 8
    for (int ch = 0; ch < CHK; ++ch)
        s += spart[((size_t)ch * Bn + b) * (129 * CF) + rem];
    ctot[idx] = (float)s * INV_SCALE;
}

// ---------------- glob + area conversion ----------------
__global__ void glob_k(const float* __restrict__ ctot, const int* __restrict__ apart,
                       float* __restrict__ glob,
                       float* __restrict__ areaf, float* __restrict__ area_out) {
    int idx = blockIdx.x * 256 + threadIdx.x;
    if (idx < Bn * CF) {
        int b = idx / CF, c = idx - b * CF;
        float s = 0.f;
        for (int cell = 0; cell < 129; ++cell)
            s += ctot[((size_t)(b * 129 + cell)) * CF + c];
        glob[idx] = s * (1.0f / (float)HWn);
    }
    if (idx < Nn) {
        int b = idx >> 7, cell = idx & 127;
        int s = 0;
        #pragma unroll 8
        for (int ch = 0; ch < CHK; ++ch)
            s += apart[(ch * Bn + b) * Kc + cell];
        float a = (float)s;
        areaf[idx] = a;
        area_out[idx] = a;
    }
}

// ---------------- emb GEMM: [512,768]x[768,256], 2-row strips, K/4 waves ------
__global__ __launch_bounds__(256) void gemm_emb_k(
        const float* __restrict__ ctot, const float* __restrict__ glob,
        const float* __restrict__ areaf, const float* __restrict__ Bw,
        float* __restrict__ C) {
    int row0 = blockIdx.x * 2;
    __shared__ float As[2 * 768];
    __shared__ float part[2048];
    __shared__ float rina[2];
    int t = threadIdx.x, lane = t & 63, w = t >> 6;
    if (t < 2) rina[t] = 1.f / fmaxf(areaf[row0 + t], 1.f);
    __syncthreads();
    for (int idx = t; idx < 2 * 768; idx += 256) {
        int r = idx / 768, k = idx - r * 768;
        int row = row0 + r;
        float v;
        if (k < CF) {
            int bb = row >> 7, cell = (row & 127) + 1;
            v = ctot[((size_t)(bb * 129 + cell)) * CF + k] * rina[r];
        } else {
            v = glob[(row >> 7) * CF + (k - CF)];
        }
        As[idx] = v;
    }
    __syncthreads();
    float acc[2][4] = {{0,0,0,0},{0,0,0,0}};
    const int KQ = 192;
    const float* bp = Bw + (size_t)(w * KQ) * 256 + lane * 4;
    #pragma unroll 8
    for (int k = 0; k < KQ; ++k) {
        float4 bv = *(const float4*)(bp + (size_t)k * 256);
        float a0 = As[w * KQ + k], a1 = As[768 + w * KQ + k];
        acc[0][0] = fmaf(a0, bv.x, acc[0][0]); acc[0][1] = fmaf(a0, bv.y, acc[0][1]);
        acc[0][2] = fmaf(a0, bv.z, acc[0][2]); acc[0][3] = fmaf(a0, bv.w, acc[0][3]);
        acc[1][0] = fmaf(a1, bv.x, acc[1][0]); acc[1][1] = fmaf(a1, bv.y, acc[1][1]);
        acc[1][2] = fmaf(a1, bv.z, acc[1][2]); acc[1][3] = fmaf(a1, bv.w, acc[1][3]);
    }
    *(float4*)&part[(w * 2 + 0) * 256 + lane * 4] = make_float4(acc[0][0], acc[0][1], acc[0][2], acc[0][3]);
    *(float4*)&part[(w * 2 + 1) * 256 + lane * 4] = make_float4(acc[1][0], acc[1][1], acc[1][2], acc[1][3]);
    __syncthreads();
    #pragma unroll
    for (int i2 = 0; i2 < 2; ++i2) {
        int idx = i2 * 256 + t, r = idx >> 8, c = idx & 255;
        float s = part[r*256+c] + part[(2+r)*256+c] + part[(4+r)*256+c] + part[(6+r)*256+c];
        C[(size_t)(row0 + r) * En + c] = s;
    }
}

// ---------------- per-batch mean of emb over K cells ----------------
__global__ void patch_mean_k(const float* __restrict__ emb, float* __restrict__ ep) {
    int b = blockIdx.x, j = threadIdx.x;
    float s = 0.f;
    for (int r = 0; r < Kc; r++) s += emb[(size_t)(b * Kc + r) * En + j];
    ep[b * En + j] = s * (1.f / (float)Kc);
}

// ---------------- comp MLP + softmax: one block per batch ----------------
__global__ void comp_mlp_k(const float* __restrict__ ep, const float* __restrict__ w1,
                           const float* __restrict__ w2, float* __restrict__ comp_ws,
                           float* __restrict__ comp_out) {
    int b = blockIdx.x, j = threadIdx.x;
    __shared__ float h[En];
    __shared__ float c[NCn];
    float acc = 0.f;
    #pragma unroll 8
    for (int k = 0; k < En; k++) acc = fmaf(ep[b * En + k], w1[(size_t)k * En + j], acc);
    h[j] = fmaxf(acc, 0.f);
    __syncthreads();
    if (j < NCn) {
        float a2 = 0.f;
        #pragma unroll 8
        for (int k = 0; k < En; k++) a2 = fmaf(h[k], w2[(size_t)k * NCn + j], a2);
        c[j] = a2;
    }
    __syncthreads();
    if (j == 0) {
        float m = c[0];
        for (int q = 1; q < NCn; q++) m = fmaxf(m, c[q]);
        float s = 0.f;
        for (int q = 0; q < NCn; q++) { c[q] = __expf(c[q] - m); s += c[q]; }
        float inv = 1.f / s;
        for (int q = 0; q < NCn; q++) c[q] *= inv;
    }
    __syncthreads();
    if (j < NCn) {
        comp_ws[b * NCn + j] = c[j];
        comp_out[b * NCn + j] = c[j];
    }
}

// ---------------- fused hist: out_ct = relu(emb@w1)@w2, 2-row strips ----------
__global__ __launch_bounds__(256) void fused_hist_k(
        const float* __restrict__ emb, const float* __restrict__ w1,
        const float* __restrict__ w2, float* __restrict__ out) {
    int row0 = blockIdx.x * 2;
    __shared__ float As[2 * En];
    __shared__ float part[2048];
    __shared__ float Hs[2 * En];
    int t = threadIdx.x, lane = t & 63, w = t >> 6;
    if (t < 128) *(float4*)&As[t * 4] = *(const float4*)(emb + (size_t)row0 * En + t * 4);
    __syncthreads();
    float acc[2][4] = {{0,0,0,0},{0,0,0,0}};
    const float* bp = w1 + (size_t)(w * 64) * 256 + lane * 4;
    #pragma unroll 8
    for (int k = 0; k < 64; ++k) {
        float4 bv = *(const float4*)(bp + (size_t)k * 256);
        float a0 = As[w * 64 + k], a1 = As[256 + w * 64 + k];
        acc[0][0] = fmaf(a0, bv.x, acc[0][0]); acc[0][1] = fmaf(a0, bv.y, acc[0][1]);
        acc[0][2] = fmaf(a0, bv.z, acc[0][2]); acc[0][3] = fmaf(a0, bv.w, acc[0][3]);
        acc[1][0] = fmaf(a1, bv.x, acc[1][0]); acc[1][1] = fmaf(a1, bv.y, acc[1][1]);
        acc[1][2] = fmaf(a1, bv.z, acc[1][2]); acc[1][3] = fmaf(a1, bv.w, acc[1][3]);
    }
    *(float4*)&part[(w * 2 + 0) * 256 + lane * 4] = make_float4(acc[0][0], acc[0][1], acc[0][2], acc[0][3]);
    *(float4*)&part[(w * 2 + 1) * 256 + lane * 4] = make_float4(acc[1][0], acc[1][1], acc[1][2], acc[1][3]);
    __syncthreads();
    #pragma unroll
    for (int i2 = 0; i2 < 2; ++i2) {
        int idx = i2 * 256 + t, r = idx >> 8, c = idx & 255;
        float s = part[r*256+c] + part[(2+r)*256+c] + part[(4+r)*256+c] + part[(6+r)*256+c];
        Hs[r * 256 + c] = fmaxf(s, 0.f);
    }
    __syncthreads();
    if (t < 32) {
        int r = t >> 4, j = t & 15;
        float a2 = 0.f;
        #pragma unroll 8
        for (int k = 0; k < En; k++) a2 = fmaf(Hs[r * 256 + k], w2[(size_t)k * NCn + j], a2);
        out[(size_t)(row0 + r) * NCn + j] = a2;
    }
}

// ---------------- fused branch: relu(emb@w1)@w2 -> softmax -> @ref ------------
__global__ __launch_bounds__(256) void fused_branch_k(
        const float* __restrict__ emb, const float* __restrict__ wref_w1,
        const float* __restrict__ wref_w2, const float* __restrict__ ref,
        float* __restrict__ refw) {
    int i = blockIdx.y, row0 = blockIdx.x * 2;
    const float* w1 = wref_w1 + (size_t)i * En * En;
    const float* w2 = wref_w2 + (size_t)i * En * Rn;
    __shared__ float As[2 * En];
    __shared__ float part[2048];
    __shared__ float Hs[2 * En];
    __shared__ float RW[2 * Rn];
    int t = threadIdx.x, lane = t & 63, w = t >> 6;
    if (t < 128) *(float4*)&As[t * 4] = *(const float4*)(emb + (size_t)row0 * En + t * 4);
    __syncthreads();
    {   // stage1: Hs = relu(A @ w1)  K=256
        float acc[2][4] = {{0,0,0,0},{0,0,0,0}};
        const float* bp = w1 + (size_t)(w * 64) * 256 + lane * 4;
        #pragma unroll 8
        for (int k = 0; k < 64; ++k) {
            float4 bv = *(const float4*)(bp + (size_t)k * 256);
            float a0 = As[w * 64 + k], a1 = As[256 + w * 64 + k];
            acc[0][0] = fmaf(a0, bv.x, acc[0][0]); acc[0][1] = fmaf(a0, bv.y, acc[0][1]);
            acc[0][2] = fmaf(a0, bv.z, acc[0][2]); acc[0][3] = fmaf(a0, bv.w, acc[0][3]);
            acc[1][0] = fmaf(a1, bv.x, acc[1][0]); acc[1][1] = fmaf(a1, bv.y, acc[1][1]);
            acc[1][2] = fmaf(a1, bv.z, acc[1][2]); acc[1][3] = fmaf(a1, bv.w, acc[1][3]);
        }
        *(float4*)&part[(w * 2 + 0) * 256 + lane * 4] = make_float4(acc[0][0], acc[0][1], acc[0][2], acc[0][3]);
        *(float4*)&part[(w * 2 + 1) * 256 + lane * 4] = make_float4(acc[1][0], acc[1][1], acc[1][2], acc[1][3]);
    }
    __syncthreads();
    #pragma unroll
    for (int i2 = 0; i2 < 2; ++i2) {
        int idx = i2 * 256 + t, r = idx >> 8, c = idx & 255;
        float s = part[r*256+c] + part[(2+r)*256+c] + part[(4+r)*256+c] + part[(6+r)*256+c];
        Hs[r * 256 + c] = fmaxf(s, 0.f);
    }
    __syncthreads();
    {   // stage2: rw = Hs @ w2  K=256, N=64
        float a0 = 0.f, a1 = 0.f;
        const float* bp = w2 + (size_t)(w * 64) * 64 + lane;
        #pragma unroll 8
        for (int k = 0; k < 64; ++k) {
            float bv = bp[(size_t)k * 64];
            a0 = fmaf(Hs[w * 64 + k], bv, a0);
            a1 = fmaf(Hs[256 + w * 64 + k], bv, a1);
        }
        part[(w * 2 + 0) * 64 + lane] = a0;
        part[(w * 2 + 1) * 64 + lane] = a1;
    }
    __syncthreads();
    if (t < 128) {
        int r = t >> 6, c = t & 63;
        RW[r * 64 + c] = part[r*64+c] + part[(2+r)*64+c] + part[(4+r)*64+c] + part[(6+r)*64+c];
    }
    __syncthreads();
    if (w < 2) {   // softmax over 64, wave w = row w
        float v = RW[w * 64 + lane];
        float m = v;
        #pragma unroll
        for (int o = 32; o > 0; o >>= 1) m = fmaxf(m, __shfl_xor(m, o));
        float e = __expf(v - m), s = e;
        #pragma unroll
        for (int o = 32; o > 0; o >>= 1) s += __shfl_xor(s, o);
        RW[w * 64 + lane] = e / s;
    }
    __syncthreads();
    {   // stage4: refw strip = RW @ ref  K=64, N=512, K-halves over t>>7
        int q = t & 127, kh = t >> 7;
        float acc[2][4] = {{0,0,0,0},{0,0,0,0}};
        const float* bp = ref + (size_t)(kh * 32) * 512 + q * 4;
        #pragma unroll 8
        for (int k = 0; k < 32; ++k) {
            float4 bv = *(const float4*)(bp + (size_t)k * 512);
            float a0 = RW[kh * 32 + k], a1 = RW[64 + kh * 32 + k];
            acc[0][0] = fmaf(a0, bv.x, acc[0][0]); acc[0][1] = fmaf(a0, bv.y, acc[0][1]);
            acc[0][2] = fmaf(a0, bv.z, acc[0][2]); acc[0][3] = fmaf(a0, bv.w, acc[0][3]);
            acc[1][0] = fmaf(a1, bv.x, acc[1][0]); acc[1][1] = fmaf(a1, bv.y, acc[1][1]);
            acc[1][2] = fmaf(a1, bv.z, acc[1][2]); acc[1][3] = fmaf(a1, bv.w, acc[1][3]);
        }
        *(float4*)&part[(kh * 2 + 0) * 512 + q * 4] = make_float4(acc[0][0], acc[0][1], acc[0][2], acc[0][3]);
        *(float4*)&part[(kh * 2 + 1) * 512 + q * 4] = make_float4(acc[1][0], acc[1][1], acc[1][2], acc[1][3]);
    }
    __syncthreads();
    float* op = refw + ((size_t)i * Nn + row0) * Gn;
    #pragma unroll
    for (int i2 = 0; i2 < 4; ++i2) {
        int idx = i2 * 256 + t, r = idx >> 9, c = idx & 511;
        op[(size_t)r * Gn + c] = part[r * 512 + c] + part[(2 + r) * 512 + c];
    }
}

// ---------------- fused K/V projections ----------------
__global__ __launch_bounds__(256) void fused_kv_k(
        const float* __restrict__ refw, const float* __restrict__ ca_wk,
        const float* __restrict__ ca_wv, float* __restrict__ kws,
        float* __restrict__ vws) {
    int i = blockIdx.y, row0 = blockIdx.x * 2;
    const float* wk = ca_wk + (size_t)i * Gn * En;
    const float* wv = ca_wv + (size_t)i * Gn * En;
    __shared__ float As[2 * Gn];
    __shared__ float part[2048];
    int t = threadIdx.x, lane = t & 63, w = t >> 6;
    const float* rp = refw + ((size_t)i * Nn + row0) * Gn;
    *(float4*)&As[t * 4] = *(const float4*)(rp + t * 4);
    __syncthreads();
    int which = w >> 1, half = w & 1;
    const float* Bp = (which ? wv : wk) + (size_t)(half * 256) * En + lane * 4;
    float acc[2][4] = {{0,0,0,0},{0,0,0,0}};
    #pragma unroll 8
    for (int k = 0; k < 256; ++k) {
        float4 bv = *(const float4*)(Bp + (size_t)k * En);
        float a0 = As[half * 256 + k], a1 = As[512 + half * 256 + k];
        acc[0][0] = fmaf(a0, bv.x, acc[0][0]); acc[0][1] = fmaf(a0, bv.y, acc[0][1]);
        acc[0][2] = fmaf(a0, bv.z, acc[0][2]); acc[0][3] = fmaf(a0, bv.w, acc[0][3]);
        acc[1][0] = fmaf(a1, bv.x, acc[1][0]); acc[1][1] = fmaf(a1, bv.y, acc[1][1]);
        acc[1][2] = fmaf(a1, bv.z, acc[1][2]); acc[1][3] = fmaf(a1, bv.w, acc[1][3]);
    }
    *(float4*)&part[(w * 2 + 0) * 256 + lane * 4] = make_float4(acc[0][0], acc[0][1], acc[0][2], acc[0][3]);
    *(float4*)&part[(w * 2 + 1) * 256 + lane * 4] = make_float4(acc[1][0], acc[1][1], acc[1][2], acc[1][3]);
    __syncthreads();
    #pragma unroll
    for (int i2 = 0; i2 < 2; ++i2) {
        int idx = i2 * 256 + t, r = idx >> 8, c = idx & 255;
        float sk = part[r * 256 + c] + part[(2 + r) * 256 + c];
        float sv = part[(4 + r) * 256 + c] + part[(6 + r) * 256 + c];
        kws[((size_t)i * Nn + row0 + r) * En + c] = sk;
        vws[((size_t)i * Nn + row0 + r) * En + c] = sv;
    }
}

// ---------------- generic batched row-strip GEMM (ow only) ----------------
template <int R, bool RELU>
__global__ void gemm_rows_k(const float* __restrict__ A, long long sA,
                            const float* __restrict__ Bw, long long sB,
                            float* __restrict__ C, long long sC,
                            int M, int N, int K) {
    int i = blockIdx.y;
    A += (size_t)i * sA; Bw += (size_t)i * sB; C += (size_t)i * sC;
    int row0 = blockIdx.x * R;
    extern __shared__ float As[];
    for (int idx = threadIdx.x; idx < R * K; idx += blockDim.x)
        As[idx] = A[(size_t)(row0 + idx / K) * K + (idx % K)];
    __syncthreads();
    for (int j = threadIdx.x; j < N; j += blockDim.x) {
        float acc[R];
        #pragma unroll
        for (int r = 0; r < R; r++) acc[r] = 0.f;
        const float* bp = Bw + j;
        #pragma unroll 8
        for (int k = 0; k < K; k++) {
            float bv = bp[(size_t)k * N];
            #pragma unroll
            for (int r = 0; r < R; r++) acc[r] = fmaf(As[r * K + k], bv, acc[r]);
        }
        #pragma unroll
        for (int r = 0; r < R; r++) {
            float v = acc[r];
            if (RELU) v = fmaxf(v, 0.f);
            C[(size_t)(row0 + r) * N + j] = v;
        }
    }
}

// ---------------- collapsed attention ----------------
__global__ __launch_bounds__(256) void attn_k(
        const float* __restrict__ compw, const float* __restrict__ wq,
        const float* __restrict__ kmat, const float* __restrict__ vmat,
        float* __restrict__ o4) {
    int i = blockIdx.y, b = blockIdx.x & 3, h = blockIdx.x >> 2;
    const float* wqi = wq + (size_t)i * NCn * En;
    const float* km = kmat + (size_t)i * Nn * En;
    const float* vm = vmat + (size_t)i * Nn * En;
    __shared__ float q[DHn];
    __shared__ float p[Nn];
    __shared__ float red[4];
    __shared__ float pvp[8][33];
    int t = threadIdx.x;
    if (t < DHn) {
        float acc = 0.f;
        #pragma unroll
        for (int c = 0; c < NCn; c++)
            acc = fmaf(compw[b * NCn + c], wqi[(size_t)c * En + h * DHn + t], acc);
        q[t] = acc;
    }
    __syncthreads();
    const float scale = 0.17677669529663687f;
    float sv0, sv1;
    {
        const float* kr = km + (size_t)t * En + h * DHn;
        float a = 0.f;
        #pragma unroll
        for (int d = 0; d < DHn; d++) a = fmaf(q[d], kr[d], a);
        sv0 = a * scale;
        kr += (size_t)256 * En;
        a = 0.f;
        #pragma unroll
        for (int d = 0; d < DHn; d++) a = fmaf(q[d], kr[d], a);
        sv1 = a * scale;
    }
    float lm = fmaxf(sv0, sv1);
    #pragma unroll
    for (int o = 32; o > 0; o >>= 1) lm = fmaxf(lm, __shfl_xor(lm, o));
    if ((t & 63) == 0) red[t >> 6] = lm;
    __syncthreads();
    float m = fmaxf(fmaxf(red[0], red[1]), fmaxf(red[2], red[3]));
    __syncthreads();
    float e0 = __expf(sv0 - m), e1 = __expf(sv1 - m);
    p[t] = e0; p[t + 256] = e1;
    float ls = e0 + e1;
    #pragma unroll
    for (int o = 32; o > 0; o >>= 1) ls += __shfl_xor(ls, o);
    if ((t & 63) == 0) red[t >> 6] = ls;
    __syncthreads();
    float ssum = red[0] + red[1] + red[2] + red[3];
    int d = t & 31, seg = t >> 5;
    float acc = 0.f;
    const float* vp = vm + (size_t)(seg * 64) * En + h * DHn + d;
    #pragma unroll 8
    for (int j = 0; j < 64; ++j) acc = fmaf(p[seg * 64 + j], vp[(size_t)j * En], acc);
    pvp[seg][d] = acc;
    __syncthreads();
    if (t < DHn) {
        float o = 0.f;
        #pragma unroll
        for (int s8 = 0; s8 < 8; ++s8) o += pvp[s8][t];
        o4[((size_t)i * Bn + b) * En + h * DHn + t] = o / ssum;
    }
}

// ---------------- out_exprs = relu(refw + ow[batch]), vectorized --------------
__global__ void add_relu_k(const float* __restrict__ refw, const float* __restrict__ ow,
                           float* __restrict__ out) {
    int i = blockIdx.y, n = blockIdx.x, b = n >> 7;
    const float4* rr = (const float4*)(refw + ((size_t)i * Nn + n) * Gn);
    const float4* oo = (const float4*)(ow + ((size_t)i * Bn + b) * Gn);
    float4* op = (float4*)(out + (size_t)i * (Nn * Gn) + (size_t)n * Gn);
    int j = threadIdx.x;
    float4 a = rr[j], o = oo[j];
    op[j] = make_float4(fmaxf(a.x + o.x, 0.f), fmaxf(a.y + o.y, 0.f),
                        fmaxf(a.z + o.z, 0.f), fmaxf(a.w + o.w, 0.f));
}

// ---------------- fused genes: gh = relu(e0@gw1); octe = gh@gw2 ---------------
__global__ __launch_bounds__(256) void fused_genes_k(
        const float* __restrict__ e0, const float* __restrict__ gw1,
        const float* __restrict__ gw2, float* __restrict__ gh,
        float* __restrict__ octe) {
    int row0 = blockIdx.x * 2;
    __shared__ float As[2 * Gn];
    __shared__ float part[2048];
    __shared__ float Hs[2 * En];
    int t = threadIdx.x, lane = t & 63, w = t >> 6;
    *(float4*)&As[t * 4] = *(const float4*)(e0 + (size_t)row0 * Gn + t * 4);
    __syncthreads();
    {
        float acc[2][4] = {{0,0,0,0},{0,0,0,0}};
        const float* bp = gw1 + (size_t)(w * 128) * 256 + lane * 4;
        #pragma unroll 8
        for (int k = 0; k < 128; ++k) {
            float4 bv = *(const float4*)(bp + (size_t)k * 256);
            float a0 = As[w * 128 + k], a1 = As[512 + w * 128 + k];
            acc[0][0] = fmaf(a0, bv.x, acc[0][0]); acc[0][1] = fmaf(a0, bv.y, acc[0][1]);
            acc[0][2] = fmaf(a0, bv.z, acc[0][2]); acc[0][3] = fmaf(a0, bv.w, acc[0][3]);
            acc[1][0] = fmaf(a1, bv.x, acc[1][0]); acc[1][1] = fmaf(a1, bv.y, acc[1][1]);
            acc[1][2] = fmaf(a1, bv.z, acc[1][2]); acc[1][3] = fmaf(a1, bv.w, acc[1][3]);
        }
        *(float4*)&part[(w * 2 + 0) * 256 + lane * 4] = make_float4(acc[0][0], acc[0][1], acc[0][2], acc[0][3]);
        *(float4*)&part[(w * 2 + 1) * 256 + lane * 4] = make_float4(acc[1][0], acc[1][1], acc[1][2], acc[1][3]);
    }
    __syncthreads();
    #pragma unroll
    for (int i2 = 0; i2 < 2; ++i2) {
        int idx = i2 * 256 + t, r = idx >> 8, c = idx & 255;
        float s = part[r*256+c] + part[(2+r)*256+c] + part[(4+r)*256+c] + part[(6+r)*256+c];
        float v = fmaxf(s, 0.f);
        Hs[r * 256 + c] = v;
        gh[(size_t)(row0 + r) * En + c] = v;
    }
    __syncthreads();
    if (t < 32) {
        int r = t >> 4, j = t & 15;
        float a2 = 0.f;
        #pragma unroll 8
        for (int k = 0; k < En; k++) a2 = fmaf(Hs[r * 256 + k], gw2[(size_t)k * NCn + j], a2);
        octe[(size_t)(row0 + r) * NCn + j] = a2;
    }
}

extern "C" void kernel_launch(void* const* d_in, const int* in_sizes, int n_in,
                              void* d_out, int out_size, void* d_ws, size_t ws_size,
                              hipStream_t stream) {
    const float* hd1     = (const float*)d_in[0];
    const float* h1      = (const float*)d_in[1];
    const float* ref     = (const float*)d_in[2];
    const float* embed_w = (const float*)d_in[3];
    const float* comp_w1 = (const float*)d_in[4];
    const float* comp_w2 = (const float*)d_in[5];
    const float* hist_w1 = (const float*)d_in[6];
    const float* hist_w2 = (const float*)d_in[7];
    const float* genes_w1= (const float*)d_in[8];
    const float* genes_w2= (const float*)d_in[9];
    const float* wref_w1 = (const float*)d_in[10];
    const float* wref_w2 = (const float*)d_in[11];
    const float* ca_wq   = (const float*)d_in[12];
    const float* ca_wk   = (const float*)d_in[13];
    const float* ca_wv   = (const float*)d_in[14];
    const float* ca_wo   = (const float*)d_in[15];
    const int*   mask    = (const int*)d_in[16];

    float* out = (float*)d_out;
    const size_t o_ct   = 0;
    const size_t o_e0   = 8192;
    const size_t o_octe = 8192 + 3 * 262144;
    const size_t o_gh   = o_octe + 8192;
    const size_t o_comp = o_gh + 131072;
    const size_t o_area = o_comp + 64;

    // workspace: [ spart i32 | apart i32 | ctot f32 | floats... ]
    int*  spart = (int*)d_ws;                        // 32*4*129*384 = 6,340,608
    int*  apart = spart + (size_t)CHK * Bn * 129 * CF; // 32*4*128 = 16384
    float* ctot = (float*)(apart + CHK * Bn * Kc);   // 4*129*384 = 198144
    float* glob = ctot + Bn * 129 * CF;              // 1536
    float* areaf = glob + 1536;                      // 512
    float* emb   = areaf + 512;                      // 131072
    float* ep    = emb + 131072;                     // 1024
    float* compw = ep + 1024;                        // 64
    float* refw  = compw + 64;                       // 786432
    float* kws   = refw + 786432;                    // 393216
    float* vws   = kws + 393216;                     // 393216
    float* o4    = vws + 393216;                     // 3072
    float* ow    = o4 + 3072;                        // 6144

    area_k<<<dim3(CHK, Bn), 256, 0, stream>>>(mask, apart);
    segreduce3_k<<<dim3(CHK, CF / TC2, Bn), 256, 0, stream>>>(hd1, h1, mask, spart);
    reduce_k<<<(Bn * 129 * CF + 255) / 256, 256, 0, stream>>>(spart, ctot);
    glob_k<<<6, 256, 0, stream>>>(ctot, apart, glob, areaf, out + o_area);
    gemm_emb_k<<<Nn / 2, 256, 0, stream>>>(ctot, glob, areaf, embed_w, emb);
    patch_mean_k<<<Bn, 256, 0, stream>>>(emb, ep);
    comp_mlp_k<<<Bn, 256, 0, stream>>>(ep, comp_w1, comp_w2, compw, out + o_comp);

    fused_hist_k<<<Nn / 2, 256, 0, stream>>>(emb, hist_w1, hist_w2, out + o_ct);
    fused_branch_k<<<dim3(Nn / 2, 3), 256, 0, stream>>>(emb, wref_w1, wref_w2, ref, refw);
    fused_kv_k<<<dim3(Nn / 2, 3), 256, 0, stream>>>(refw, ca_wk, ca_wv, kws, vws);
    attn_k<<<dim3(HEADSn * Bn, 3), 256, 0, stream>>>(compw, ca_wq, kws, vws, o4);
    gemm_rows_k<4, false><<<dim3(1, 3), 256, 4 * 256 * 4, stream>>>(
        o4, (long long)Bn * En, ca_wo, (long long)En * Gn, ow, (long long)Bn * Gn, Bn, Gn, En);
    add_relu_k<<<dim3(Nn, 3), 128, 0, stream>>>(refw, ow, out + o_e0);

    fused_genes_k<<<Nn / 2, 256, 0, stream>>>(out + o_e0, genes_w1, genes_w2,
                                              out + o_gh, out + o_octe);
}

// Round 2
// 646.916 us; speedup vs baseline: 1.1000x; 1.0157x over previous
//
#include <hip/hip_runtime.h>
#include <hip/hip_bf16.h>

#define Bn 4
#define C1n 256
#define C2n 128
#define CF 384
#define HWn 65536
#define Kc 128
#define Nn 512          // B*K
#define En 256
#define NCn 16
#define Gn 512
#define Rn 64
#define HEADSn 8
#define DHn 32

#define CHK 32          // chunks per image
#define PCH2 (HWn/CHK)  // 2048 pixels per chunk
#define TC2 32          // channels per block

#define SCALE_F 1048576.0f
#define INV_SCALE (1.0f/1048576.0f)

typedef unsigned long long ull;

// ---------------- area histogram: per-chunk partial counts, no atomics -------
__global__ __launch_bounds__(256) void area_k(const int* __restrict__ mask,
                                              int* __restrict__ apart) {
    int chunk = blockIdx.x, b = blockIdx.y;
    __shared__ int hist[4][129];
    int t = threadIdx.x, w = t >> 6;
    for (int i = t; i < 4 * 129; i += 256) ((int*)hist)[i] = 0;
    __syncthreads();
    const int* mp = mask + (size_t)b * HWn + chunk * PCH2;
    #pragma unroll
    for (int it = 0; it < PCH2 / 1024; ++it) {
        int4 v = *(const int4*)(mp + it * 1024 + t * 4);
        atomicAdd(&hist[w][v.x], 1);
        atomicAdd(&hist[w][v.y], 1);
        atomicAdd(&hist[w][v.z], 1);
        atomicAdd(&hist[w][v.w], 1);
    }
    __syncthreads();
    if (t < 128)
        apart[(chunk * Bn + b) * Kc + t] =
            hist[0][t+1] + hist[1][t+1] + hist[2][t+1] + hist[3][t+1];
}

// ---------------- segment reduce: direct i32 LDS atomics, stride-33 swizzle --
// grid (32 chunks, 12 ch-groups, 4 batches), 256 threads.
// bins[id*33 + c]: bank = (id + c) & 31, so the 8 random ids per wave land on
// 8 shifted bank-octets -> ~2-3-way aliasing, no transpose/barriers needed.
// Per-chunk bin sums are bounded (|sum| << 2^11) so i32 at 2^20 scale is safe;
// i32 partials reduce bit-exactly into i64 downstream.
__global__ __launch_bounds__(256) void segreduce3_k(
        const float* __restrict__ hd1, const float* __restrict__ h1,
        const int* __restrict__ mask,
        int* __restrict__ spart) {
    int chunk = blockIdx.x, cg = blockIdx.y, b = blockIdx.z;
    int c0 = cg * TC2;
    const float* base = (c0 < C1n)
        ? hd1 + ((size_t)(b * C1n + c0)) * HWn
        : h1  + ((size_t)(b * C2n + (c0 - C1n))) * HWn;
    const int* mp = mask + (size_t)b * HWn + chunk * PCH2;

    __shared__ int bins[129 * 33];             // 17 KB, stride-33 anti-conflict

    int t = threadIdx.x;
    int cL = t >> 3, l8 = t & 7;               // lane = (channel, pixel-slot)
    for (int i = t; i < 129 * 33; i += 256) bins[i] = 0;
    __syncthreads();

    const float* rowp = base + (size_t)cL * HWn;
    for (int px0 = l8 * 4; px0 < PCH2; px0 += 64) {
        float4 v0 = *(const float4*)(rowp + px0);
        float4 v1 = *(const float4*)(rowp + px0 + 32);
        int4 i0 = *(const int4*)(mp + px0);
        int4 i1 = *(const int4*)(mp + px0 + 32);
        atomicAdd(&bins[i0.x * 33 + cL], __float2int_rn(v0.x * SCALE_F));
        atomicAdd(&bins[i0.y * 33 + cL], __float2int_rn(v0.y * SCALE_F));
        atomicAdd(&bins[i0.z * 33 + cL], __float2int_rn(v0.z * SCALE_F));
        atomicAdd(&bins[i0.w * 33 + cL], __float2int_rn(v0.w * SCALE_F));
        atomicAdd(&bins[i1.x * 33 + cL], __float2int_rn(v1.x * SCALE_F));
        atomicAdd(&bins[i1.y * 33 + cL], __float2int_rn(v1.y * SCALE_F));
        atomicAdd(&bins[i1.z * 33 + cL], __float2int_rn(v1.z * SCALE_F));
        atomicAdd(&bins[i1.w * 33 + cL], __float2int_rn(v1.w * SCALE_F));
    }
    __syncthreads();
    // flush: plain coalesced stores of the full partial slab
    for (int i = t; i < 129 * TC2; i += 256) {
        int cell = i >> 5, cc = i & 31;
        spart[((size_t)(chunk * Bn + b) * 129 + cell) * CF + c0 + cc] = bins[cell * 33 + cc];
    }
}

// ---------------- reduce per-chunk i32 partials -> f32 cell totals ----------
__global__ void reduce_k(const int* __restrict__ spart, float* __restrict__ ctot) {
    int idx = blockIdx.x * 256 + threadIdx.x;      // over 4*129*384 = 198144
    if (idx >= Bn * 129 * CF) return;
    int b = idx / (129 * CF);
    int rem = idx - b * 129 * CF;                  // cell*CF + c
    long long s = 0;
    #pragma unroll 8
    for (int ch = 0; ch < CHK; ++ch)
        s += spart[((size_t)ch * Bn + b) * (129 * CF) + rem];
    ctot[idx] = (float)s * INV_SCALE;
}

// ---------------- glob + area conversion ----------------
__global__ void glob_k(const float* __restrict__ ctot, const int* __restrict__ apart,
                       float* __restrict__ glob,
                       float* __restrict__ areaf, float* __restrict__ area_out) {
    int idx = blockIdx.x * 256 + threadIdx.x;
    if (idx < Bn * CF) {
        int b = idx / CF, c = idx - b * CF;
        float s = 0.f;
        for (int cell = 0; cell < 129; ++cell)
            s += ctot[((size_t)(b * 129 + cell)) * CF + c];
        glob[idx] = s * (1.0f / (float)HWn);
    }
    if (idx < Nn) {
        int b = idx >> 7, cell = idx & 127;
        int s = 0;
        #pragma unroll 8
        for (int ch = 0; ch < CHK; ++ch)
            s += apart[(ch * Bn + b) * Kc + cell];
        float a = (float)s;
        areaf[idx] = a;
        area_out[idx] = a;
    }
}

// ---------------- emb GEMM: [512,768]x[768,256], 2-row strips, K/4 waves ------
__global__ __launch_bounds__(256) void gemm_emb_k(
        const float* __restrict__ ctot, const float* __restrict__ glob,
        const float* __restrict__ areaf, const float* __restrict__ Bw,
        float* __restrict__ C) {
    int row0 = blockIdx.x * 2;
    __shared__ float As[2 * 768];
    __shared__ float part[2048];
    __shared__ float rina[2];
    int t = threadIdx.x, lane = t & 63, w = t >> 6;
    if (t < 2) rina[t] = 1.f / fmaxf(areaf[row0 + t], 1.f);
    __syncthreads();
    for (int idx = t; idx < 2 * 768; idx += 256) {
        int r = idx / 768, k = idx - r * 768;
        int row = row0 + r;
        float v;
        if (k < CF) {
            int bb = row >> 7, cell = (row & 127) + 1;
            v = ctot[((size_t)(bb * 129 + cell)) * CF + k] * rina[r];
        } else {
            v = glob[(row >> 7) * CF + (k - CF)];
        }
        As[idx] = v;
    }
    __syncthreads();
    float acc[2][4] = {{0,0,0,0},{0,0,0,0}};
    const int KQ = 192;
    const float* bp = Bw + (size_t)(w * KQ) * 256 + lane * 4;
    #pragma unroll 8
    for (int k = 0; k < KQ; ++k) {
        float4 bv = *(const float4*)(bp + (size_t)k * 256);
        float a0 = As[w * KQ + k], a1 = As[768 + w * KQ + k];
        acc[0][0] = fmaf(a0, bv.x, acc[0][0]); acc[0][1] = fmaf(a0, bv.y, acc[0][1]);
        acc[0][2] = fmaf(a0, bv.z, acc[0][2]); acc[0][3] = fmaf(a0, bv.w, acc[0][3]);
        acc[1][0] = fmaf(a1, bv.x, acc[1][0]); acc[1][1] = fmaf(a1, bv.y, acc[1][1]);
        acc[1][2] = fmaf(a1, bv.z, acc[1][2]); acc[1][3] = fmaf(a1, bv.w, acc[1][3]);
    }
    *(float4*)&part[(w * 2 + 0) * 256 + lane * 4] = make_float4(acc[0][0], acc[0][1], acc[0][2], acc[0][3]);
    *(float4*)&part[(w * 2 + 1) * 256 + lane * 4] = make_float4(acc[1][0], acc[1][1], acc[1][2], acc[1][3]);
    __syncthreads();
    #pragma unroll
    for (int i2 = 0; i2 < 2; ++i2) {
        int idx = i2 * 256 + t, r = idx >> 8, c = idx & 255;
        float s = part[r*256+c] + part[(2+r)*256+c] + part[(4+r)*256+c] + part[(6+r)*256+c];
        C[(size_t)(row0 + r) * En + c] = s;
    }
}

// ---------------- comp MLP (+fused patch mean) + softmax: 1 block/batch ------
__global__ void comp_mlp_k(const float* __restrict__ emb, const float* __restrict__ w1,
                           const float* __restrict__ w2, float* __restrict__ comp_ws,
                           float* __restrict__ comp_out) {
    int b = blockIdx.x, j = threadIdx.x;
    __shared__ float eps[En];
    __shared__ float h[En];
    __shared__ float c[NCn];
    float s0 = 0.f;
    for (int r = 0; r < Kc; r++) s0 += emb[(size_t)(b * Kc + r) * En + j];
    eps[j] = s0 * (1.f / (float)Kc);
    __syncthreads();
    float acc = 0.f;
    #pragma unroll 8
    for (int k = 0; k < En; k++) acc = fmaf(eps[k], w1[(size_t)k * En + j], acc);
    h[j] = fmaxf(acc, 0.f);
    __syncthreads();
    if (j < NCn) {
        float a2 = 0.f;
        #pragma unroll 8
        for (int k = 0; k < En; k++) a2 = fmaf(h[k], w2[(size_t)k * NCn + j], a2);
        c[j] = a2;
    }
    __syncthreads();
    if (j == 0) {
        float m = c[0];
        for (int q = 1; q < NCn; q++) m = fmaxf(m, c[q]);
        float s = 0.f;
        for (int q = 0; q < NCn; q++) { c[q] = __expf(c[q] - m); s += c[q]; }
        float inv = 1.f / s;
        for (int q = 0; q < NCn; q++) c[q] *= inv;
    }
    __syncthreads();
    if (j < NCn) {
        comp_ws[b * NCn + j] = c[j];
        comp_out[b * NCn + j] = c[j];
    }
}

// ---------------- fused hist: out_ct = relu(emb@w1)@w2, 2-row strips ----------
__global__ __launch_bounds__(256) void fused_hist_k(
        const float* __restrict__ emb, const float* __restrict__ w1,
        const float* __restrict__ w2, float* __restrict__ out) {
    int row0 = blockIdx.x * 2;
    __shared__ float As[2 * En];
    __shared__ float part[2048];
    __shared__ float Hs[2 * En];
    int t = threadIdx.x, lane = t & 63, w = t >> 6;
    if (t < 128) *(float4*)&As[t * 4] = *(const float4*)(emb + (size_t)row0 * En + t * 4);
    __syncthreads();
    float acc[2][4] = {{0,0,0,0},{0,0,0,0}};
    const float* bp = w1 + (size_t)(w * 64) * 256 + lane * 4;
    #pragma unroll 8
    for (int k = 0; k < 64; ++k) {
        float4 bv = *(const float4*)(bp + (size_t)k * 256);
        float a0 = As[w * 64 + k], a1 = As[256 + w * 64 + k];
        acc[0][0] = fmaf(a0, bv.x, acc[0][0]); acc[0][1] = fmaf(a0, bv.y, acc[0][1]);
        acc[0][2] = fmaf(a0, bv.z, acc[0][2]); acc[0][3] = fmaf(a0, bv.w, acc[0][3]);
        acc[1][0] = fmaf(a1, bv.x, acc[1][0]); acc[1][1] = fmaf(a1, bv.y, acc[1][1]);
        acc[1][2] = fmaf(a1, bv.z, acc[1][2]); acc[1][3] = fmaf(a1, bv.w, acc[1][3]);
    }
    *(float4*)&part[(w * 2 + 0) * 256 + lane * 4] = make_float4(acc[0][0], acc[0][1], acc[0][2], acc[0][3]);
    *(float4*)&part[(w * 2 + 1) * 256 + lane * 4] = make_float4(acc[1][0], acc[1][1], acc[1][2], acc[1][3]);
    __syncthreads();
    #pragma unroll
    for (int i2 = 0; i2 < 2; ++i2) {
        int idx = i2 * 256 + t, r = idx >> 8, c = idx & 255;
        float s = part[r*256+c] + part[(2+r)*256+c] + part[(4+r)*256+c] + part[(6+r)*256+c];
        Hs[r * 256 + c] = fmaxf(s, 0.f);
    }
    __syncthreads();
    if (t < 32) {
        int r = t >> 4, j = t & 15;
        float a2 = 0.f;
        #pragma unroll 8
        for (int k = 0; k < En; k++) a2 = fmaf(Hs[r * 256 + k], w2[(size_t)k * NCn + j], a2);
        out[(size_t)(row0 + r) * NCn + j] = a2;
    }
}

// ---------------- fused branch: relu(emb@w1)@w2 -> softmax -> @ref ------------
// 4-row strips: halves weight re-streaming (768 -> 384 blocks)
__global__ __launch_bounds__(256) void fused_branch_k(
        const float* __restrict__ emb, const float* __restrict__ wref_w1,
        const float* __restrict__ wref_w2, const float* __restrict__ ref,
        float* __restrict__ refw) {
    int i = blockIdx.y, row0 = blockIdx.x * 4;
    const float* w1 = wref_w1 + (size_t)i * En * En;
    const float* w2 = wref_w2 + (size_t)i * En * Rn;
    __shared__ float As[4 * En];       // 4 KB
    __shared__ float part[4096];       // 16 KB
    __shared__ float Hs[4 * En];       // 4 KB
    __shared__ float RW[4 * Rn];       // 1 KB
    int t = threadIdx.x, lane = t & 63, w = t >> 6;
    *(float4*)&As[t * 4] = *(const float4*)(emb + (size_t)row0 * En + t * 4);
    __syncthreads();
    {   // stage1: Hs = relu(A @ w1)  K=256 split over 4 waves
        float acc[4][4] = {{0,0,0,0},{0,0,0,0},{0,0,0,0},{0,0,0,0}};
        const float* bp = w1 + (size_t)(w * 64) * 256 + lane * 4;
        #pragma unroll 4
        for (int k = 0; k < 64; ++k) {
            float4 bv = *(const float4*)(bp + (size_t)k * 256);
            #pragma unroll
            for (int r = 0; r < 4; ++r) {
                float a = As[r * 256 + w * 64 + k];
                acc[r][0] = fmaf(a, bv.x, acc[r][0]); acc[r][1] = fmaf(a, bv.y, acc[r][1]);
                acc[r][2] = fmaf(a, bv.z, acc[r][2]); acc[r][3] = fmaf(a, bv.w, acc[r][3]);
            }
        }
        #pragma unroll
        for (int r = 0; r < 4; ++r)
            *(float4*)&part[(w * 4 + r) * 256 + lane * 4] =
                make_float4(acc[r][0], acc[r][1], acc[r][2], acc[r][3]);
    }
    __syncthreads();
    #pragma unroll
    for (int i2 = 0; i2 < 4; ++i2) {
        int idx = i2 * 256 + t, r = idx >> 8, c = idx & 255;
        float s = part[r*256+c] + part[(4+r)*256+c] + part[(8+r)*256+c] + part[(12+r)*256+c];
        Hs[r * 256 + c] = fmaxf(s, 0.f);
    }
    __syncthreads();
    {   // stage2: rw = Hs @ w2  K=256, N=64
        float a[4] = {0.f, 0.f, 0.f, 0.f};
        const float* bp = w2 + (size_t)(w * 64) * 64 + lane;
        #pragma unroll 8
        for (int k = 0; k < 64; ++k) {
            float bv = bp[(size_t)k * 64];
            #pragma unroll
            for (int r = 0; r < 4; ++r) a[r] = fmaf(Hs[r * 256 + w * 64 + k], bv, a[r]);
        }
        #pragma unroll
        for (int r = 0; r < 4; ++r) part[(w * 4 + r) * 64 + lane] = a[r];
    }
    __syncthreads();
    {   // reduce 4 wave-partials: 4 rows x 64 = 256 entries = blockDim
        int r = t >> 6, c = t & 63;
        RW[r * 64 + c] = part[r*64+c] + part[(4+r)*64+c] + part[(8+r)*64+c] + part[(12+r)*64+c];
    }
    __syncthreads();
    {   // softmax over 64, wave w = row w (all 4 waves active)
        float v = RW[w * 64 + lane];
        float m = v;
        #pragma unroll
        for (int o = 32; o > 0; o >>= 1) m = fmaxf(m, __shfl_xor(m, o));
        float e = __expf(v - m), s = e;
        #pragma unroll
        for (int o = 32; o > 0; o >>= 1) s += __shfl_xor(s, o);
        RW[w * 64 + lane] = e / s;
    }
    __syncthreads();
    {   // stage4: refw strip = RW @ ref  K=64, N=512, K-halves over t>>7
        int q = t & 127, kh = t >> 7;
        float acc[4][4] = {{0,0,0,0},{0,0,0,0},{0,0,0,0},{0,0,0,0}};
        const float* bp = ref + (size_t)(kh * 32) * 512 + q * 4;
        #pragma unroll 4
        for (int k = 0; k < 32; ++k) {
            float4 bv = *(const float4*)(bp + (size_t)k * 512);
            #pragma unroll
            for (int r = 0; r < 4; ++r) {
                float a = RW[r * 64 + kh * 32 + k];
                acc[r][0] = fmaf(a, bv.x, acc[r][0]); acc[r][1] = fmaf(a, bv.y, acc[r][1]);
                acc[r][2] = fmaf(a, bv.z, acc[r][2]); acc[r][3] = fmaf(a, bv.w, acc[r][3]);
            }
        }
        #pragma unroll
        for (int r = 0; r < 4; ++r)
            *(float4*)&part[(kh * 4 + r) * 512 + q * 4] =
                make_float4(acc[r][0], acc[r][1], acc[r][2], acc[r][3]);
    }
    __syncthreads();
    float* op = refw + ((size_t)i * Nn + row0) * Gn;
    #pragma unroll
    for (int i2 = 0; i2 < 8; ++i2) {
        int idx = i2 * 256 + t, r = idx >> 9, c = idx & 511;
        op[(size_t)r * Gn + c] = part[r * 512 + c] + part[(4 + r) * 512 + c];
    }
}

// ---------------- fused K/V projections: 8-row strips (1 CU round) -----------
__global__ __launch_bounds__(256) void fused_kv_k(
        const float* __restrict__ refw, const float* __restrict__ ca_wk,
        const float* __restrict__ ca_wv, float* __restrict__ kws,
        float* __restrict__ vws) {
    int i = blockIdx.y, row0 = blockIdx.x * 8;
    const float* wk = ca_wk + (size_t)i * Gn * En;
    const float* wv = ca_wv + (size_t)i * Gn * En;
    __shared__ float As[8 * Gn];       // 16 KB
    __shared__ float part[8192];       // 32 KB
    int t = threadIdx.x, lane = t & 63, w = t >> 6;
    const float* rp = refw + ((size_t)i * Nn + row0) * Gn;
    #pragma unroll
    for (int q = 0; q < 4; ++q)
        *(float4*)&As[q * 1024 + t * 4] = *(const float4*)(rp + q * 1024 + t * 4);
    __syncthreads();
    int which = w >> 1, half = w & 1;
    const float* Bp = (which ? wv : wk) + (size_t)(half * 256) * En + lane * 4;
    float acc[8][4];
    #pragma unroll
    for (int r = 0; r < 8; ++r) { acc[r][0]=0.f; acc[r][1]=0.f; acc[r][2]=0.f; acc[r][3]=0.f; }
    #pragma unroll 4
    for (int k = 0; k < 256; ++k) {
        float4 bv = *(const float4*)(Bp + (size_t)k * En);
        #pragma unroll
        for (int r = 0; r < 8; ++r) {
            float a = As[r * 512 + half * 256 + k];
            acc[r][0] = fmaf(a, bv.x, acc[r][0]); acc[r][1] = fmaf(a, bv.y, acc[r][1]);
            acc[r][2] = fmaf(a, bv.z, acc[r][2]); acc[r][3] = fmaf(a, bv.w, acc[r][3]);
        }
    }
    #pragma unroll
    for (int r = 0; r < 8; ++r)
        *(float4*)&part[(w * 8 + r) * 256 + lane * 4] =
            make_float4(acc[r][0], acc[r][1], acc[r][2], acc[r][3]);
    __syncthreads();
    #pragma unroll
    for (int i2 = 0; i2 < 8; ++i2) {
        int idx = i2 * 256 + t, r = idx >> 8, c = idx & 255;
        float sk = part[r * 256 + c] + part[(8 + r) * 256 + c];
        float sv = part[(16 + r) * 256 + c] + part[(24 + r) * 256 + c];
        kws[((size_t)i * Nn + row0 + r) * En + c] = sk;
        vws[((size_t)i * Nn + row0 + r) * En + c] = sv;
    }
}

// ---------------- generic batched row-strip GEMM (ow only) ----------------
template <int R, bool RELU>
__global__ void gemm_rows_k(const float* __restrict__ A, long long sA,
                            const float* __restrict__ Bw, long long sB,
                            float* __restrict__ C, long long sC,
                            int M, int N, int K) {
    int i = blockIdx.y;
    A += (size_t)i * sA; Bw += (size_t)i * sB; C += (size_t)i * sC;
    int row0 = blockIdx.x * R;
    extern __shared__ float As[];
    for (int idx = threadIdx.x; idx < R * K; idx += blockDim.x)
        As[idx] = A[(size_t)(row0 + idx / K) * K + (idx % K)];
    __syncthreads();
    for (int j = threadIdx.x; j < N; j += blockDim.x) {
        float acc[R];
        #pragma unroll
        for (int r = 0; r < R; r++) acc[r] = 0.f;
        const float* bp = Bw + j;
        #pragma unroll 8
        for (int k = 0; k < K; k++) {
            float bv = bp[(size_t)k * N];
            #pragma unroll
            for (int r = 0; r < R; r++) acc[r] = fmaf(As[r * K + k], bv, acc[r]);
        }
        #pragma unroll
        for (int r = 0; r < R; r++) {
            float v = acc[r];
            if (RELU) v = fmaxf(v, 0.f);
            C[(size_t)(row0 + r) * N + j] = v;
        }
    }
}

// ---------------- collapsed attention ----------------
__global__ __launch_bounds__(256) void attn_k(
        const float* __restrict__ compw, const float* __restrict__ wq,
        const float* __restrict__ kmat, const float* __restrict__ vmat,
        float* __restrict__ o4) {
    int i = blockIdx.y, b = blockIdx.x & 3, h = blockIdx.x >> 2;
    const float* wqi = wq + (size_t)i * NCn * En;
    const float* km = kmat + (size_t)i * Nn * En;
    const float* vm = vmat + (size_t)i * Nn * En;
    __shared__ float q[DHn];
    __shared__ float p[Nn];
    __shared__ float red[4];
    __shared__ float pvp[8][33];
    int t = threadIdx.x;
    if (t < DHn) {
        float acc = 0.f;
        #pragma unroll
        for (int c = 0; c < NCn; c++)
            acc = fmaf(compw[b * NCn + c], wqi[(size_t)c * En + h * DHn + t], acc);
        q[t] = acc;
    }
    __syncthreads();
    const float scale = 0.17677669529663687f;
    float sv0, sv1;
    {
        const float* kr = km + (size_t)t * En + h * DHn;
        float a = 0.f;
        #pragma unroll
        for (int d = 0; d < DHn; d++) a = fmaf(q[d], kr[d], a);
        sv0 = a * scale;
        kr += (size_t)256 * En;
        a = 0.f;
        #pragma unroll
        for (int d = 0; d < DHn; d++) a = fmaf(q[d], kr[d], a);
        sv1 = a * scale;
    }
    float lm = fmaxf(sv0, sv1);
    #pragma unroll
    for (int o = 32; o > 0; o >>= 1) lm = fmaxf(lm, __shfl_xor(lm, o));
    if ((t & 63) == 0) red[t >> 6] = lm;
    __syncthreads();
    float m = fmaxf(fmaxf(red[0], red[1]), fmaxf(red[2], red[3]));
    __syncthreads();
    float e0 = __expf(sv0 - m), e1 = __expf(sv1 - m);
    p[t] = e0; p[t + 256] = e1;
    float ls = e0 + e1;
    #pragma unroll
    for (int o = 32; o > 0; o >>= 1) ls += __shfl_xor(ls, o);
    if ((t & 63) == 0) red[t >> 6] = ls;
    __syncthreads();
    float ssum = red[0] + red[1] + red[2] + red[3];
    int d = t & 31, seg = t >> 5;
    float acc = 0.f;
    const float* vp = vm + (size_t)(seg * 64) * En + h * DHn + d;
    #pragma unroll 8
    for (int j = 0; j < 64; ++j) acc = fmaf(p[seg * 64 + j], vp[(size_t)j * En], acc);
    pvp[seg][d] = acc;
    __syncthreads();
    if (t < DHn) {
        float o = 0.f;
        #pragma unroll
        for (int s8 = 0; s8 < 8; ++s8) o += pvp[s8][t];
        o4[((size_t)i * Bn + b) * En + h * DHn + t] = o / ssum;
    }
}

// ---------------- out_exprs = relu(refw + ow[batch]), vectorized --------------
__global__ void add_relu_k(const float* __restrict__ refw, const float* __restrict__ ow,
                           float* __restrict__ out) {
    int i = blockIdx.y, n = blockIdx.x, b = n >> 7;
    const float4* rr = (const float4*)(refw + ((size_t)i * Nn + n) * Gn);
    const float4* oo = (const float4*)(ow + ((size_t)i * Bn + b) * Gn);
    float4* op = (float4*)(out + (size_t)i * (Nn * Gn) + (size_t)n * Gn);
    int j = threadIdx.x;
    float4 a = rr[j], o = oo[j];
    op[j] = make_float4(fmaxf(a.x + o.x, 0.f), fmaxf(a.y + o.y, 0.f),
                        fmaxf(a.z + o.z, 0.f), fmaxf(a.w + o.w, 0.f));
}

// ---------------- fused genes: gh = relu(e0@gw1); octe = gh@gw2 ---------------
__global__ __launch_bounds__(256) void fused_genes_k(
        const float* __restrict__ e0, const float* __restrict__ gw1,
        const float* __restrict__ gw2, float* __restrict__ gh,
        float* __restrict__ octe) {
    int row0 = blockIdx.x * 2;
    __shared__ float As[2 * Gn];
    __shared__ float part[2048];
    __shared__ float Hs[2 * En];
    int t = threadIdx.x, lane = t & 63, w = t >> 6;
    *(float4*)&As[t * 4] = *(const float4*)(e0 + (size_t)row0 * Gn + t * 4);
    __syncthreads();
    {
        float acc[2][4] = {{0,0,0,0},{0,0,0,0}};
        const float* bp = gw1 + (size_t)(w * 128) * 256 + lane * 4;
        #pragma unroll 8
        for (int k = 0; k < 128; ++k) {
            float4 bv = *(const float4*)(bp + (size_t)k * 256);
            float a0 = As[w * 128 + k], a1 = As[512 + w * 128 + k];
            acc[0][0] = fmaf(a0, bv.x, acc[0][0]); acc[0][1] = fmaf(a0, bv.y, acc[0][1]);
            acc[0][2] = fmaf(a0, bv.z, acc[0][2]); acc[0][3] = fmaf(a0, bv.w, acc[0][3]);
            acc[1][0] = fmaf(a1, bv.x, acc[1][0]); acc[1][1] = fmaf(a1, bv.y, acc[1][1]);
            acc[1][2] = fmaf(a1, bv.z, acc[1][2]); acc[1][3] = fmaf(a1, bv.w, acc[1][3]);
        }
        *(float4*)&part[(w * 2 + 0) * 256 + lane * 4] = make_float4(acc[0][0], acc[0][1], acc[0][2], acc[0][3]);
        *(float4*)&part[(w * 2 + 1) * 256 + lane * 4] = make_float4(acc[1][0], acc[1][1], acc[1][2], acc[1][3]);
    }
    __syncthreads();
    #pragma unroll
    for (int i2 = 0; i2 < 2; ++i2) {
        int idx = i2 * 256 + t, r = idx >> 8, c = idx & 255;
        float s = part[r*256+c] + part[(2+r)*256+c] + part[(4+r)*256+c] + part[(6+r)*256+c];
        float v = fmaxf(s, 0.f);
        Hs[r * 256 + c] = v;
        gh[(size_t)(row0 + r) * En + c] = v;
    }
    __syncthreads();
    if (t < 32) {
        int r = t >> 4, j = t & 15;
        float a2 = 0.f;
        #pragma unroll 8
        for (int k = 0; k < En; k++) a2 = fmaf(Hs[r * 256 + k], gw2[(size_t)k * NCn + j], a2);
        octe[(size_t)(row0 + r) * NCn + j] = a2;
    }
}

extern "C" void kernel_launch(void* const* d_in, const int* in_sizes, int n_in,
                              void* d_out, int out_size, void* d_ws, size_t ws_size,
                              hipStream_t stream) {
    const float* hd1     = (const float*)d_in[0];
    const float* h1      = (const float*)d_in[1];
    const float* ref     = (const float*)d_in[2];
    const float* embed_w = (const float*)d_in[3];
    const float* comp_w1 = (const float*)d_in[4];
    const float* comp_w2 = (const float*)d_in[5];
    const float* hist_w1 = (const float*)d_in[6];
    const float* hist_w2 = (const float*)d_in[7];
    const float* genes_w1= (const float*)d_in[8];
    const float* genes_w2= (const float*)d_in[9];
    const float* wref_w1 = (const float*)d_in[10];
    const float* wref_w2 = (const float*)d_in[11];
    const float* ca_wq   = (const float*)d_in[12];
    const float* ca_wk   = (const float*)d_in[13];
    const float* ca_wv   = (const float*)d_in[14];
    const float* ca_wo   = (const float*)d_in[15];
    const int*   mask    = (const int*)d_in[16];

    float* out = (float*)d_out;
    const size_t o_ct   = 0;
    const size_t o_e0   = 8192;
    const size_t o_octe = 8192 + 3 * 262144;
    const size_t o_gh   = o_octe + 8192;
    const size_t o_comp = o_gh + 131072;
    const size_t o_area = o_comp + 64;

    // workspace: [ spart i32 | apart i32 | ctot f32 | floats... ]
    int*  spart = (int*)d_ws;                        // 32*4*129*384 = 6,340,608
    int*  apart = spart + (size_t)CHK * Bn * 129 * CF; // 32*4*128 = 16384
    float* ctot = (float*)(apart + CHK * Bn * Kc);   // 4*129*384 = 198144
    float* glob = ctot + Bn * 129 * CF;              // 1536
    float* areaf = glob + 1536;                      // 512
    float* emb   = areaf + 512;                      // 131072
    float* compw = emb + 131072;                     // 64
    float* refw  = compw + 64;                       // 786432
    float* kws   = refw + 786432;                    // 393216
    float* vws   = kws + 393216;                     // 393216
    float* o4    = vws + 393216;                     // 3072
    float* ow    = o4 + 3072;                        // 6144

    area_k<<<dim3(CHK, Bn), 256, 0, stream>>>(mask, apart);
    segreduce3_k<<<dim3(CHK, CF / TC2, Bn), 256, 0, stream>>>(hd1, h1, mask, spart);
    reduce_k<<<(Bn * 129 * CF + 255) / 256, 256, 0, stream>>>(spart, ctot);
    glob_k<<<6, 256, 0, stream>>>(ctot, apart, glob, areaf, out + o_area);
    gemm_emb_k<<<Nn / 2, 256, 0, stream>>>(ctot, glob, areaf, embed_w, emb);
    comp_mlp_k<<<Bn, 256, 0, stream>>>(emb, comp_w1, comp_w2, compw, out + o_comp);

    fused_hist_k<<<Nn / 2, 256, 0, stream>>>(emb, hist_w1, hist_w2, out + o_ct);
    fused_branch_k<<<dim3(Nn / 4, 3), 256, 0, stream>>>(emb, wref_w1, wref_w2, ref, refw);
    fused_kv_k<<<dim3(Nn / 8, 3), 256, 0, stream>>>(refw, ca_wk, ca_wv, kws, vws);
    attn_k<<<dim3(HEADSn * Bn, 3), 256, 0, stream>>>(compw, ca_wq, kws, vws, o4);
    gemm_rows_k<1, false><<<dim3(Bn, 3), 256, 256 * 4, stream>>>(
        o4, (long long)Bn * En, ca_wo, (long long)En * Gn, ow, (long long)Bn * Gn, Bn, Gn, En);
    add_relu_k<<<dim3(Nn, 3), 128, 0, stream>>>(refw, ow, out + o_e0);

    fused_genes_k<<<Nn / 2, 256, 0, stream>>>(out + o_e0, genes_w1, genes_w2,
                                              out + o_gh, out + o_octe);
}

// Round 4
// 579.253 us; speedup vs baseline: 1.2285x; 1.1168x over previous
//
#include <hip/hip_runtime.h>
#include <hip/hip_bf16.h>

#define Bn 4
#define C1n 256
#define C2n 128
#define CF 384
#define HWn 65536
#define Kc 128
#define Nn 512          // B*K
#define En 256
#define NCn 16
#define Gn 512
#define Rn 64
#define HEADSn 8
#define DHn 32

#define CHK 32          // chunks per image
#define PCH2 (HWn/CHK)  // 2048 pixels per chunk
#define TC2 32          // channels per block

#define SCALE_F 1048576.0f
#define INV_SCALE (1.0f/1048576.0f)

typedef unsigned long long ull;

// ---------------- area histogram + zero the atomic accumulators --------------
// zeroed region: glob(1536) | ep(1024) | ow(6144) contiguous = 8704 floats
__global__ __launch_bounds__(256) void area_k(const int* __restrict__ mask,
                                              int* __restrict__ apart,
                                              float* __restrict__ zbase) {
    int chunk = blockIdx.x, b = blockIdx.y;
    __shared__ int hist[4][129];
    int t = threadIdx.x, w = t >> 6;
    int bid = b * CHK + chunk;
    if (bid == 0)
        for (int i = t; i < 8704; i += 256) zbase[i] = 0.f;
    for (int i = t; i < 4 * 129; i += 256) ((int*)hist)[i] = 0;
    __syncthreads();
    const int* mp = mask + (size_t)b * HWn + chunk * PCH2;
    #pragma unroll
    for (int it = 0; it < PCH2 / 1024; ++it) {
        int4 v = *(const int4*)(mp + it * 1024 + t * 4);
        atomicAdd(&hist[w][v.x], 1);
        atomicAdd(&hist[w][v.y], 1);
        atomicAdd(&hist[w][v.z], 1);
        atomicAdd(&hist[w][v.w], 1);
    }
    __syncthreads();
    if (t < 128)
        apart[(chunk * Bn + b) * Kc + t] =
            hist[0][t+1] + hist[1][t+1] + hist[2][t+1] + hist[3][t+1];
}

// ---------------- segment reduce: direct i32 LDS atomics, stride-33 swizzle --
__global__ __launch_bounds__(256) void segreduce3_k(
        const float* __restrict__ hd1, const float* __restrict__ h1,
        const int* __restrict__ mask,
        int* __restrict__ spart) {
    int chunk = blockIdx.x, cg = blockIdx.y, b = blockIdx.z;
    int c0 = cg * TC2;
    const float* base = (c0 < C1n)
        ? hd1 + ((size_t)(b * C1n + c0)) * HWn
        : h1  + ((size_t)(b * C2n + (c0 - C1n))) * HWn;
    const int* mp = mask + (size_t)b * HWn + chunk * PCH2;

    __shared__ int bins[129 * 33];             // 17 KB, stride-33 anti-conflict

    int t = threadIdx.x;
    int cL = t >> 3, l8 = t & 7;               // lane = (channel, pixel-slot)
    for (int i = t; i < 129 * 33; i += 256) bins[i] = 0;
    __syncthreads();

    const float* rowp = base + (size_t)cL * HWn;
    for (int px0 = l8 * 4; px0 < PCH2; px0 += 64) {
        float4 v0 = *(const float4*)(rowp + px0);
        float4 v1 = *(const float4*)(rowp + px0 + 32);
        int4 i0 = *(const int4*)(mp + px0);
        int4 i1 = *(const int4*)(mp + px0 + 32);
        atomicAdd(&bins[i0.x * 33 + cL], __float2int_rn(v0.x * SCALE_F));
        atomicAdd(&bins[i0.y * 33 + cL], __float2int_rn(v0.y * SCALE_F));
        atomicAdd(&bins[i0.z * 33 + cL], __float2int_rn(v0.z * SCALE_F));
        atomicAdd(&bins[i0.w * 33 + cL], __float2int_rn(v0.w * SCALE_F));
        atomicAdd(&bins[i1.x * 33 + cL], __float2int_rn(v1.x * SCALE_F));
        atomicAdd(&bins[i1.y * 33 + cL], __float2int_rn(v1.y * SCALE_F));
        atomicAdd(&bins[i1.z * 33 + cL], __float2int_rn(v1.z * SCALE_F));
        atomicAdd(&bins[i1.w * 33 + cL], __float2int_rn(v1.w * SCALE_F));
    }
    __syncthreads();
    for (int i = t; i < 129 * TC2; i += 256) {
        int cell = i >> 5, cc = i & 31;
        spart[((size_t)(chunk * Bn + b) * 129 + cell) * CF + c0 + cc] = bins[cell * 33 + cc];
    }
}

// ---------------- reduce partials -> ctot; glob via atomics; areaf ----------
__global__ void reduce_k(const int* __restrict__ spart, const int* __restrict__ apart,
                         float* __restrict__ ctot, float* __restrict__ glob,
                         float* __restrict__ areaf, float* __restrict__ area_out) {
    int idx = blockIdx.x * 256 + threadIdx.x;      // over 4*129*384 = 198144
    if (idx < Bn * 129 * CF) {
        int b = idx / (129 * CF);
        int rem = idx - b * 129 * CF;              // cell*CF + c
        int cell = rem / CF, c = rem - cell * CF;
        long long s = 0;
        #pragma unroll 8
        for (int ch = 0; ch < CHK; ++ch)
            s += spart[((size_t)ch * Bn + b) * (129 * CF) + rem];
        float val = (float)s * INV_SCALE;
        ctot[idx] = val;
        atomicAdd(&glob[b * CF + c], val * (1.0f / (float)HWn));
    }
    if (idx < Nn) {
        int b = idx >> 7, cell = idx & 127;
        int s = 0;
        #pragma unroll 8
        for (int ch = 0; ch < CHK; ++ch)
            s += apart[(ch * Bn + b) * Kc + cell];
        float a = (float)s;
        areaf[idx] = a;
        area_out[idx] = a;
    }
}

// ---------------- emb GEMM + fused patch-mean accumulation -------------------
__global__ __launch_bounds__(256) void gemm_emb_k(
        const float* __restrict__ ctot, const float* __restrict__ glob,
        const float* __restrict__ areaf, const float* __restrict__ Bw,
        float* __restrict__ C, float* __restrict__ ep) {
    int row0 = blockIdx.x * 2;
    __shared__ float As[2 * 768];
    __shared__ float part[2048];
    __shared__ float rina[2];
    int t = threadIdx.x, lane = t & 63, w = t >> 6;
    if (t < 2) rina[t] = 1.f / fmaxf(areaf[row0 + t], 1.f);
    __syncthreads();
    for (int idx = t; idx < 2 * 768; idx += 256) {
        int r = idx / 768, k = idx - r * 768;
        int row = row0 + r;
        float v;
        if (k < CF) {
            int bb = row >> 7, cell = (row & 127) + 1;
            v = ctot[((size_t)(bb * 129 + cell)) * CF + k] * rina[r];
        } else {
            v = glob[(row >> 7) * CF + (k - CF)];
        }
        As[idx] = v;
    }
    __syncthreads();
    float acc[2][4] = {{0,0,0,0},{0,0,0,0}};
    const int KQ = 192;
    const float* bp = Bw + (size_t)(w * KQ) * 256 + lane * 4;
    #pragma unroll 8
    for (int k = 0; k < KQ; ++k) {
        float4 bv = *(const float4*)(bp + (size_t)k * 256);
        float a0 = As[w * KQ + k], a1 = As[768 + w * KQ + k];
        acc[0][0] = fmaf(a0, bv.x, acc[0][0]); acc[0][1] = fmaf(a0, bv.y, acc[0][1]);
        acc[0][2] = fmaf(a0, bv.z, acc[0][2]); acc[0][3] = fmaf(a0, bv.w, acc[0][3]);
        acc[1][0] = fmaf(a1, bv.x, acc[1][0]); acc[1][1] = fmaf(a1, bv.y, acc[1][1]);
        acc[1][2] = fmaf(a1, bv.z, acc[1][2]); acc[1][3] = fmaf(a1, bv.w, acc[1][3]);
    }
    *(float4*)&part[(w * 2 + 0) * 256 + lane * 4] = make_float4(acc[0][0], acc[0][1], acc[0][2], acc[0][3]);
    *(float4*)&part[(w * 2 + 1) * 256 + lane * 4] = make_float4(acc[1][0], acc[1][1], acc[1][2], acc[1][3]);
    __syncthreads();
    #pragma unroll
    for (int i2 = 0; i2 < 2; ++i2) {
        int idx = i2 * 256 + t, r = idx >> 8, c = idx & 255;
        float s = part[r*256+c] + part[(2+r)*256+c] + part[(4+r)*256+c] + part[(6+r)*256+c];
        C[(size_t)(row0 + r) * En + c] = s;
        atomicAdd(&ep[((row0 + r) >> 7) * En + c], s * (1.f / (float)Kc));
    }
}

// ---------------- comp MLP + softmax (mean precomputed in ep) ----------------
__global__ void comp_mlp_k(const float* __restrict__ ep, const float* __restrict__ w1,
                           const float* __restrict__ w2, float* __restrict__ comp_ws,
                           float* __restrict__ comp_out) {
    int b = blockIdx.x, j = threadIdx.x;
    __shared__ float h[En];
    __shared__ float c[NCn];
    float acc = 0.f;
    #pragma unroll 8
    for (int k = 0; k < En; k++) acc = fmaf(ep[b * En + k], w1[(size_t)k * En + j], acc);
    h[j] = fmaxf(acc, 0.f);
    __syncthreads();
    if (j < NCn) {
        float a2 = 0.f;
        #pragma unroll 8
        for (int k = 0; k < En; k++) a2 = fmaf(h[k], w2[(size_t)k * NCn + j], a2);
        c[j] = a2;
    }
    __syncthreads();
    if (j == 0) {
        float m = c[0];
        for (int q = 1; q < NCn; q++) m = fmaxf(m, c[q]);
        float s = 0.f;
        for (int q = 0; q < NCn; q++) { c[q] = __expf(c[q] - m); s += c[q]; }
        float inv = 1.f / s;
        for (int q = 0; q < NCn; q++) c[q] *= inv;
    }
    __syncthreads();
    if (j < NCn) {
        comp_ws[b * NCn + j] = c[j];
        comp_out[b * NCn + j] = c[j];
    }
}

// ---------------- fused hist: out_ct = relu(emb@w1)@w2, 2-row strips ----------
__global__ __launch_bounds__(256) void fused_hist_k(
        const float* __restrict__ emb, const float* __restrict__ w1,
        const float* __restrict__ w2, float* __restrict__ out) {
    int row0 = blockIdx.x * 2;
    __shared__ float As[2 * En];
    __shared__ float part[2048];
    __shared__ float Hs[2 * En];
    int t = threadIdx.x, lane = t & 63, w = t >> 6;
    if (t < 128) *(float4*)&As[t * 4] = *(const float4*)(emb + (size_t)row0 * En + t * 4);
    __syncthreads();
    float acc[2][4] = {{0,0,0,0},{0,0,0,0}};
    const float* bp = w1 + (size_t)(w * 64) * 256 + lane * 4;
    #pragma unroll 8
    for (int k = 0; k < 64; ++k) {
        float4 bv = *(const float4*)(bp + (size_t)k * 256);
        float a0 = As[w * 64 + k], a1 = As[256 + w * 64 + k];
        acc[0][0] = fmaf(a0, bv.x, acc[0][0]); acc[0][1] = fmaf(a0, bv.y, acc[0][1]);
        acc[0][2] = fmaf(a0, bv.z, acc[0][2]); acc[0][3] = fmaf(a0, bv.w, acc[0][3]);
        acc[1][0] = fmaf(a1, bv.x, acc[1][0]); acc[1][1] = fmaf(a1, bv.y, acc[1][1]);
        acc[1][2] = fmaf(a1, bv.z, acc[1][2]); acc[1][3] = fmaf(a1, bv.w, acc[1][3]);
    }
    *(float4*)&part[(w * 2 + 0) * 256 + lane * 4] = make_float4(acc[0][0], acc[0][1], acc[0][2], acc[0][3]);
    *(float4*)&part[(w * 2 + 1) * 256 + lane * 4] = make_float4(acc[1][0], acc[1][1], acc[1][2], acc[1][3]);
    __syncthreads();
    #pragma unroll
    for (int i2 = 0; i2 < 2; ++i2) {
        int idx = i2 * 256 + t, r = idx >> 8, c = idx & 255;
        float s = part[r*256+c] + part[(2+r)*256+c] + part[(4+r)*256+c] + part[(6+r)*256+c];
        Hs[r * 256 + c] = fmaxf(s, 0.f);
    }
    __syncthreads();
    if (t < 32) {
        int r = t >> 4, j = t & 15;
        float a2 = 0.f;
        #pragma unroll 8
        for (int k = 0; k < En; k++) a2 = fmaf(Hs[r * 256 + k], w2[(size_t)k * NCn + j], a2);
        out[(size_t)(row0 + r) * NCn + j] = a2;
    }
}

// ---------------- fused branch: relu(emb@w1)@w2 -> softmax -> @ref ------------
__global__ __launch_bounds__(256) void fused_branch_k(
        const float* __restrict__ emb, const float* __restrict__ wref_w1,
        const float* __restrict__ wref_w2, const float* __restrict__ ref,
        float* __restrict__ refw) {
    int i = blockIdx.y, row0 = blockIdx.x * 4;
    const float* w1 = wref_w1 + (size_t)i * En * En;
    const float* w2 = wref_w2 + (size_t)i * En * Rn;
    __shared__ float As[4 * En];
    __shared__ float part[4096];
    __shared__ float Hs[4 * En];
    __shared__ float RW[4 * Rn];
    int t = threadIdx.x, lane = t & 63, w = t >> 6;
    *(float4*)&As[t * 4] = *(const float4*)(emb + (size_t)row0 * En + t * 4);
    __syncthreads();
    {   // stage1: Hs = relu(A @ w1)  K=256 split over 4 waves
        float acc[4][4] = {{0,0,0,0},{0,0,0,0},{0,0,0,0},{0,0,0,0}};
        const float* bp = w1 + (size_t)(w * 64) * 256 + lane * 4;
        #pragma unroll 4
        for (int k = 0; k < 64; ++k) {
            float4 bv = *(const float4*)(bp + (size_t)k * 256);
            #pragma unroll
            for (int r = 0; r < 4; ++r) {
                float a = As[r * 256 + w * 64 + k];
                acc[r][0] = fmaf(a, bv.x, acc[r][0]); acc[r][1] = fmaf(a, bv.y, acc[r][1]);
                acc[r][2] = fmaf(a, bv.z, acc[r][2]); acc[r][3] = fmaf(a, bv.w, acc[r][3]);
            }
        }
        #pragma unroll
        for (int r = 0; r < 4; ++r)
            *(float4*)&part[(w * 4 + r) * 256 + lane * 4] =
                make_float4(acc[r][0], acc[r][1], acc[r][2], acc[r][3]);
    }
    __syncthreads();
    #pragma unroll
    for (int i2 = 0; i2 < 4; ++i2) {
        int idx = i2 * 256 + t, r = idx >> 8, c = idx & 255;
        float s = part[r*256+c] + part[(4+r)*256+c] + part[(8+r)*256+c] + part[(12+r)*256+c];
        Hs[r * 256 + c] = fmaxf(s, 0.f);
    }
    __syncthreads();
    {   // stage2: rw = Hs @ w2  K=256, N=64
        float a[4] = {0.f, 0.f, 0.f, 0.f};
        const float* bp = w2 + (size_t)(w * 64) * 64 + lane;
        #pragma unroll 8
        for (int k = 0; k < 64; ++k) {
            float bv = bp[(size_t)k * 64];
            #pragma unroll
            for (int r = 0; r < 4; ++r) a[r] = fmaf(Hs[r * 256 + w * 64 + k], bv, a[r]);
        }
        #pragma unroll
        for (int r = 0; r < 4; ++r) part[(w * 4 + r) * 64 + lane] = a[r];
    }
    __syncthreads();
    {
        int r = t >> 6, c = t & 63;
        RW[r * 64 + c] = part[r*64+c] + part[(4+r)*64+c] + part[(8+r)*64+c] + part[(12+r)*64+c];
    }
    __syncthreads();
    {   // softmax over 64, wave w = row w
        float v = RW[w * 64 + lane];
        float m = v;
        #pragma unroll
        for (int o = 32; o > 0; o >>= 1) m = fmaxf(m, __shfl_xor(m, o));
        float e = __expf(v - m), s = e;
        #pragma unroll
        for (int o = 32; o > 0; o >>= 1) s += __shfl_xor(s, o);
        RW[w * 64 + lane] = e / s;
    }
    __syncthreads();
    {   // stage4: refw strip = RW @ ref  K=64, N=512
        int q = t & 127, kh = t >> 7;
        float acc[4][4] = {{0,0,0,0},{0,0,0,0},{0,0,0,0},{0,0,0,0}};
        const float* bp = ref + (size_t)(kh * 32) * 512 + q * 4;
        #pragma unroll 4
        for (int k = 0; k < 32; ++k) {
            float4 bv = *(const float4*)(bp + (size_t)k * 512);
            #pragma unroll
            for (int r = 0; r < 4; ++r) {
                float a = RW[r * 64 + kh * 32 + k];
                acc[r][0] = fmaf(a, bv.x, acc[r][0]); acc[r][1] = fmaf(a, bv.y, acc[r][1]);
                acc[r][2] = fmaf(a, bv.z, acc[r][2]); acc[r][3] = fmaf(a, bv.w, acc[r][3]);
            }
        }
        #pragma unroll
        for (int r = 0; r < 4; ++r)
            *(float4*)&part[(kh * 4 + r) * 512 + q * 4] =
                make_float4(acc[r][0], acc[r][1], acc[r][2], acc[r][3]);
    }
    __syncthreads();
    float* op = refw + ((size_t)i * Nn + row0) * Gn;
    #pragma unroll
    for (int i2 = 0; i2 < 8; ++i2) {
        int idx = i2 * 256 + t, r = idx >> 9, c = idx & 511;
        op[(size_t)r * Gn + c] = part[r * 512 + c] + part[(4 + r) * 512 + c];
    }
}

// ---------------- K or V projection: 8-row strips, grid (64, 2, 3) -----------
__global__ __launch_bounds__(256) void fused_kv_k(
        const float* __restrict__ refw, const float* __restrict__ ca_wk,
        const float* __restrict__ ca_wv, float* __restrict__ kws,
        float* __restrict__ vws) {
    int i = blockIdx.z, which = blockIdx.y, row0 = blockIdx.x * 8;
    const float* W = (which ? ca_wv : ca_wk) + (size_t)i * Gn * En;
    float* outp = (which ? vws : kws) + ((size_t)i * Nn + row0) * En;
    __shared__ float As[8 * Gn];       // 16 KB
    __shared__ float part[8192];       // 32 KB
    int t = threadIdx.x, lane = t & 63, w = t >> 6;
    const float* rp = refw + ((size_t)i * Nn + row0) * Gn;
    #pragma unroll
    for (int q = 0; q < 4; ++q)
        *(float4*)&As[q * 1024 + t * 4] = *(const float4*)(rp + q * 1024 + t * 4);
    __syncthreads();
    // 4 waves split K=512 into 4 x 128
    const float* Bp = W + (size_t)(w * 128) * En + lane * 4;
    float acc[8][4];
    #pragma unroll
    for (int r = 0; r < 8; ++r) { acc[r][0]=0.f; acc[r][1]=0.f; acc[r][2]=0.f; acc[r][3]=0.f; }
    #pragma unroll 4
    for (int k = 0; k < 128; ++k) {
        float4 bv = *(const float4*)(Bp + (size_t)k * En);
        #pragma unroll
        for (int r = 0; r < 8; ++r) {
            float a = As[r * 512 + w * 128 + k];
            acc[r][0] = fmaf(a, bv.x, acc[r][0]); acc[r][1] = fmaf(a, bv.y, acc[r][1]);
            acc[r][2] = fmaf(a, bv.z, acc[r][2]); acc[r][3] = fmaf(a, bv.w, acc[r][3]);
        }
    }
    #pragma unroll
    for (int r = 0; r < 8; ++r)
        *(float4*)&part[(w * 8 + r) * 256 + lane * 4] =
            make_float4(acc[r][0], acc[r][1], acc[r][2], acc[r][3]);
    __syncthreads();
    #pragma unroll
    for (int i2 = 0; i2 < 8; ++i2) {
        int idx = i2 * 256 + t, r = idx >> 8, c = idx & 255;
        float s = part[r * 256 + c] + part[(8 + r) * 256 + c]
                + part[(16 + r) * 256 + c] + part[(24 + r) * 256 + c];
        outp[(size_t)r * En + c] = s;
    }
}

// ---------------- collapsed attention + fused o@wo (atomic ow) ---------------
__global__ __launch_bounds__(256) void attn_k(
        const float* __restrict__ compw, const float* __restrict__ wq,
        const float* __restrict__ kmat, const float* __restrict__ vmat,
        const float* __restrict__ ca_wo, float* __restrict__ ow) {
    int i = blockIdx.y, b = blockIdx.x & 3, h = blockIdx.x >> 2;
    const float* wqi = wq + (size_t)i * NCn * En;
    const float* km = kmat + (size_t)i * Nn * En;
    const float* vm = vmat + (size_t)i * Nn * En;
    __shared__ float q[DHn];
    __shared__ float p[Nn];
    __shared__ float red[4];
    __shared__ float pvp[8][33];
    __shared__ float of[DHn];
    int t = threadIdx.x;
    if (t < DHn) {
        float acc = 0.f;
        #pragma unroll
        for (int c = 0; c < NCn; c++)
            acc = fmaf(compw[b * NCn + c], wqi[(size_t)c * En + h * DHn + t], acc);
        q[t] = acc;
    }
    __syncthreads();
    const float scale = 0.17677669529663687f;
    float sv0, sv1;
    {
        const float* kr = km + (size_t)t * En + h * DHn;
        float a = 0.f;
        #pragma unroll
        for (int d = 0; d < DHn; d++) a = fmaf(q[d], kr[d], a);
        sv0 = a * scale;
        kr += (size_t)256 * En;
        a = 0.f;
        #pragma unroll
        for (int d = 0; d < DHn; d++) a = fmaf(q[d], kr[d], a);
        sv1 = a * scale;
    }
    float lm = fmaxf(sv0, sv1);
    #pragma unroll
    for (int o = 32; o > 0; o >>= 1) lm = fmaxf(lm, __shfl_xor(lm, o));
    if ((t & 63) == 0) red[t >> 6] = lm;
    __syncthreads();
    float m = fmaxf(fmaxf(red[0], red[1]), fmaxf(red[2], red[3]));
    __syncthreads();
    float e0 = __expf(sv0 - m), e1 = __expf(sv1 - m);
    p[t] = e0; p[t + 256] = e1;
    float ls = e0 + e1;
    #pragma unroll
    for (int o = 32; o > 0; o >>= 1) ls += __shfl_xor(ls, o);
    if ((t & 63) == 0) red[t >> 6] = ls;
    __syncthreads();
    float ssum = red[0] + red[1] + red[2] + red[3];
    int d = t & 31, seg = t >> 5;
    float acc = 0.f;
    const float* vp = vm + (size_t)(seg * 64) * En + h * DHn + d;
    #pragma unroll 8
    for (int j = 0; j < 64; ++j) acc = fmaf(p[seg * 64 + j], vp[(size_t)j * En], acc);
    pvp[seg][d] = acc;
    __syncthreads();
    if (t < DHn) {
        float o = 0.f;
        #pragma unroll
        for (int s8 = 0; s8 < 8; ++s8) o += pvp[s8][t];
        of[t] = o / ssum;
    }
    __syncthreads();
    // fused ow partial: of(32) @ wo[h*32 : h*32+32, 0:512] -> atomic into ow
    {
        const float* wop = ca_wo + ((size_t)i * En + h * DHn) * Gn;
        float a0 = 0.f, a1 = 0.f;
        #pragma unroll
        for (int dd = 0; dd < DHn; ++dd) {
            float ov = of[dd];
            a0 = fmaf(ov, wop[(size_t)dd * Gn + t], a0);
            a1 = fmaf(ov, wop[(size_t)dd * Gn + t + 256], a1);
        }
        float* owp = ow + ((size_t)i * Bn + b) * Gn;
        atomicAdd(&owp[t], a0);
        atomicAdd(&owp[t + 256], a1);
    }
}

// ---------------- out_exprs = relu(refw + ow[batch]), i = 1,2 only -----------
__global__ void add_relu_k(const float* __restrict__ refw, const float* __restrict__ ow,
                           float* __restrict__ out) {
    int i = blockIdx.y + 1, n = blockIdx.x, b = n >> 7;
    const float4* rr = (const float4*)(refw + ((size_t)i * Nn + n) * Gn);
    const float4* oo = (const float4*)(ow + ((size_t)i * Bn + b) * Gn);
    float4* op = (float4*)(out + (size_t)i * (Nn * Gn) + (size_t)n * Gn);
    int j = threadIdx.x;
    float4 a = rr[j], o = oo[j];
    op[j] = make_float4(fmaxf(a.x + o.x, 0.f), fmaxf(a.y + o.y, 0.f),
                        fmaxf(a.z + o.z, 0.f), fmaxf(a.w + o.w, 0.f));
}

// ---------------- fused genes: e0 = relu(refw0+ow0) (written); gh; octe ------
__global__ __launch_bounds__(256) void fused_genes_k(
        const float* __restrict__ refw, const float* __restrict__ ow,
        const float* __restrict__ gw1, const float* __restrict__ gw2,
        float* __restrict__ e0, float* __restrict__ gh,
        float* __restrict__ octe) {
    int row0 = blockIdx.x * 2;
    __shared__ float As[2 * Gn];
    __shared__ float part[2048];
    __shared__ float Hs[2 * En];
    int t = threadIdx.x, lane = t & 63, w = t >> 6;
    {   // compute e0 rows = relu(refw(i=0) + ow(i=0, batch)), write + stage
        int idx4 = t * 4, r = idx4 >> 9, c = idx4 & 511;
        int row = row0 + r, b = row >> 7;
        float4 a = *(const float4*)(refw + (size_t)row * Gn + c);
        float4 o = *(const float4*)(ow + (size_t)b * Gn + c);
        float4 v = make_float4(fmaxf(a.x + o.x, 0.f), fmaxf(a.y + o.y, 0.f),
                               fmaxf(a.z + o.z, 0.f), fmaxf(a.w + o.w, 0.f));
        *(float4*)&As[idx4] = v;
        *(float4*)(e0 + (size_t)row * Gn + c) = v;
    }
    __syncthreads();
    {
        float acc[2][4] = {{0,0,0,0},{0,0,0,0}};
        const float* bp = gw1 + (size_t)(w * 128) * 256 + lane * 4;
        #pragma unroll 8
        for (int k = 0; k < 128; ++k) {
            float4 bv = *(const float4*)(bp + (size_t)k * 256);
            float a0 = As[w * 128 + k], a1 = As[512 + w * 128 + k];
            acc[0][0] = fmaf(a0, bv.x, acc[0][0]); acc[0][1] = fmaf(a0, bv.y, acc[0][1]);
            acc[0][2] = fmaf(a0, bv.z, acc[0][2]); acc[0][3] = fmaf(a0, bv.w, acc[0][3]);
            acc[1][0] = fmaf(a1, bv.x, acc[1][0]); acc[1][1] = fmaf(a1, bv.y, acc[1][1]);
            acc[1][2] = fmaf(a1, bv.z, acc[1][2]); acc[1][3] = fmaf(a1, bv.w, acc[1][3]);
        }
        *(float4*)&part[(w * 2 + 0) * 256 + lane * 4] = make_float4(acc[0][0], acc[0][1], acc[0][2], acc[0][3]);
        *(float4*)&part[(w * 2 + 1) * 256 + lane * 4] = make_float4(acc[1][0], acc[1][1], acc[1][2], acc[1][3]);
    }
    __syncthreads();
    #pragma unroll
    for (int i2 = 0; i2 < 2; ++i2) {
        int idx = i2 * 256 + t, r = idx >> 8, c = idx & 255;
        float s = part[r*256+c] + part[(2+r)*256+c] + part[(4+r)*256+c] + part[(6+r)*256+c];
        float v = fmaxf(s, 0.f);
        Hs[r * 256 + c] = v;
        gh[(size_t)(row0 + r) * En + c] = v;
    }
    __syncthreads();
    if (t < 32) {
        int r = t >> 4, j = t & 15;
        float a2 = 0.f;
        #pragma unroll 8
        for (int k = 0; k < En; k++) a2 = fmaf(Hs[r * 256 + k], gw2[(size_t)k * NCn + j], a2);
        octe[(size_t)(row0 + r) * NCn + j] = a2;
    }
}

extern "C" void kernel_launch(void* const* d_in, const int* in_sizes, int n_in,
                              void* d_out, int out_size, void* d_ws, size_t ws_size,
                              hipStream_t stream) {
    const float* hd1     = (const float*)d_in[0];
    const float* h1      = (const float*)d_in[1];
    const float* ref     = (const float*)d_in[2];
    const float* embed_w = (const float*)d_in[3];
    const float* comp_w1 = (const float*)d_in[4];
    const float* comp_w2 = (const float*)d_in[5];
    const float* hist_w1 = (const float*)d_in[6];
    const float* hist_w2 = (const float*)d_in[7];
    const float* genes_w1= (const float*)d_in[8];
    const float* genes_w2= (const float*)d_in[9];
    const float* wref_w1 = (const float*)d_in[10];
    const float* wref_w2 = (const float*)d_in[11];
    const float* ca_wq   = (const float*)d_in[12];
    const float* ca_wk   = (const float*)d_in[13];
    const float* ca_wv   = (const float*)d_in[14];
    const float* ca_wo   = (const float*)d_in[15];
    const int*   mask    = (const int*)d_in[16];

    float* out = (float*)d_out;
    const size_t o_ct   = 0;
    const size_t o_e0   = 8192;
    const size_t o_octe = 8192 + 3 * 262144;
    const size_t o_gh   = o_octe + 8192;
    const size_t o_comp = o_gh + 131072;
    const size_t o_area = o_comp + 64;

    // workspace layout (floats unless noted):
    //   spart: i32, CHK*Bn*129*CF = 6,340,608
    //   apart: i32, CHK*Bn*Kc = 16384
    //   ctot:  198144
    //   glob:  1536   -- zeroed by area_k (contiguous with ep, ow)
    //   ep:    1024   -- zeroed by area_k
    //   ow:    6144   -- zeroed by area_k
    int*  spart = (int*)d_ws;
    int*  apart = spart + (size_t)CHK * Bn * 129 * CF;
    float* ctot = (float*)(apart + CHK * Bn * Kc);
    float* glob = ctot + Bn * 129 * CF;
    float* ep   = glob + 1536;
    float* ow   = ep + 1024;
    float* areaf = ow + 6144;                        // 512
    float* emb   = areaf + 512;                      // 131072
    float* compw = emb + 131072;                     // 64
    float* refw  = compw + 64;                       // 786432
    float* kws   = refw + 786432;                    // 393216
    float* vws   = kws + 393216;                     // 393216

    area_k<<<dim3(CHK, Bn), 256, 0, stream>>>(mask, apart, glob);
    segreduce3_k<<<dim3(CHK, CF / TC2, Bn), 256, 0, stream>>>(hd1, h1, mask, spart);
    reduce_k<<<(Bn * 129 * CF + 255) / 256, 256, 0, stream>>>(
        spart, apart, ctot, glob, areaf, out + o_area);
    gemm_emb_k<<<Nn / 2, 256, 0, stream>>>(ctot, glob, areaf, embed_w, emb, ep);
    comp_mlp_k<<<Bn, 256, 0, stream>>>(ep, comp_w1, comp_w2, compw, out + o_comp);

    fused_branch_k<<<dim3(Nn / 4, 3), 256, 0, stream>>>(emb, wref_w1, wref_w2, ref, refw);
    fused_kv_k<<<dim3(Nn / 8, 2, 3), 256, 0, stream>>>(refw, ca_wk, ca_wv, kws, vws);
    attn_k<<<dim3(HEADSn * Bn, 3), 256, 0, stream>>>(compw, ca_wq, kws, vws, ca_wo, ow);
    add_relu_k<<<dim3(Nn, 2), 128, 0, stream>>>(refw, ow, out + o_e0);
    fused_genes_k<<<Nn / 2, 256, 0, stream>>>(refw, ow, genes_w1, genes_w2,
                                              out + o_e0, out + o_gh, out + o_octe);
    fused_hist_k<<<Nn / 2, 256, 0, stream>>>(emb, hist_w1, hist_w2, out + o_ct);
}